// Round 4
// baseline (423.962 us; speedup 1.0000x reference)
//
#include <hip/hip_runtime.h>
#include <hip/hip_fp16.h>

// ---------------- problem constants ----------------
#define NNODES 100000

// ---------------- workspace layout (bytes) ----------------
#define OFF_W1TH     0UL            // _Float16[256*128] frag-order = 65536
#define OFF_W1TL     65536UL        // _Float16[256*128]
#define OFF_W2TH     131072UL       // _Float16[128*64] = 16384
#define OFF_W2TL     147456UL       // _Float16[128*64] -> ends 163840
#define OFF_BCNT     163840UL       // int[512]
#define OFF_BBASE    165888UL       // int[512]
#define OFF_BCUR     167936UL       // int[512] -> ends 169984
#define OFF_ROWPTR   400128UL       // int[100001]
#define OFF_DINV     1200640UL      // float[100000]
#define OFF_COL      1605632UL      // int[1600000]  -> ends 8005632
#define OFF_EBUF     8005632UL      // int[1600000] = 6.4MB (overlaps h1g; dead before gemm1)
#define OFF_H1G      8005632UL      // half[100000*128] = 25.6MB -> ends 33605632
#define OFF_H1OUT    59205632UL     // half[100000*128] = 25.6MB -> ends 84805632
// h2g (half[100000*64]) reuses OFF_H1G (h1g dead after agg1)

typedef __attribute__((ext_vector_type(8))) _Float16 f16x8;
typedef __attribute__((ext_vector_type(4))) float f32x4;

// async global->LDS 16B per lane (dest = wave-uniform base + lane*16)
__device__ __forceinline__ void async_copy16(void* lds, const void* g) {
    __builtin_amdgcn_global_load_lds(
        (const __attribute__((address_space(1))) unsigned*)g,
        (__attribute__((address_space(3))) unsigned*)lds, 16, 0, 0);
}

// =========== CSR build via 2-level counting sort (bucket = dst>>8) ===========
__global__ __launch_bounds__(256) void bincount(const int* __restrict__ dst,
                                                int* __restrict__ bcnt, int E) {
    __shared__ int lc[512];
    int t = threadIdx.x;
    lc[t] = 0; lc[t + 256] = 0;
    __syncthreads();
    for (int e = blockIdx.x * 256 + t; e < E; e += gridDim.x * 256)
        atomicAdd(&lc[dst[e] >> 8], 1);
    __syncthreads();
    if (lc[t]) atomicAdd(&bcnt[t], lc[t]);
    if (lc[t + 256]) atomicAdd(&bcnt[t + 256], lc[t + 256]);
}

__global__ __launch_bounds__(512) void bscan(const int* __restrict__ bcnt,
                                             int* __restrict__ bbase,
                                             int* __restrict__ bcur,
                                             int* __restrict__ rowptr,
                                             int NB, int N, int E) {
    __shared__ int s[512];
    int t = threadIdx.x;
    int v = (t < NB) ? bcnt[t] : 0;
    s[t] = v;
    __syncthreads();
    for (int off = 1; off < 512; off <<= 1) {
        int add = (t >= off) ? s[t - off] : 0;
        __syncthreads();
        s[t] += add;
        __syncthreads();
    }
    if (t < NB) {
        int ex = s[t] - v;
        bbase[t] = ex;
        bcur[t] = ex;
    }
    if (t == 0) rowptr[N] = E;
}

// Phase C: bucket-grouped scatter. Packs (src | localdst<<20) into one int.
#define CHUNK 8192
__global__ __launch_bounds__(256) void binscatter(const int* __restrict__ src,
                                                  const int* __restrict__ dst,
                                                  int* __restrict__ bcur,
                                                  int* __restrict__ ebuf, int E) {
    __shared__ int lc[512];
    __shared__ int gb[512];
    int t = threadIdx.x;
    lc[t] = 0; lc[t + 256] = 0;
    __syncthreads();
    int base = blockIdx.x * CHUNK;
    int rb[32];
#pragma unroll
    for (int i = 0; i < 32; ++i) {
        int e = base + i * 256 + t;
        if (e < E) {
            int b = dst[e] >> 8;
            rb[i] = (b << 13) | atomicAdd(&lc[b], 1);  // rank < 8192 fits 13 bits
        } else rb[i] = -1;
    }
    __syncthreads();
    if (lc[t]) gb[t] = atomicAdd(&bcur[t], lc[t]);
    if (lc[t + 256]) gb[t + 256] = atomicAdd(&bcur[t + 256], lc[t + 256]);
    __syncthreads();
#pragma unroll
    for (int i = 0; i < 32; ++i) {
        if (rb[i] >= 0) {
            int e = base + i * 256 + t;
            int b = rb[i] >> 13, r = rb[i] & 8191;
            ebuf[gb[b] + r] = src[e] | ((dst[e] & 255) << 20);
        }
    }
}

__global__ __launch_bounds__(256) void buildcsr(const int* __restrict__ ebuf,
                                                const int* __restrict__ bbase,
                                                const int* __restrict__ bcnt,
                                                int* __restrict__ rowptr,
                                                int* __restrict__ colarr,
                                                float* __restrict__ dinv, int N) {
    int b = blockIdx.x;
    int t = threadIdx.x;
    int start = bbase[b];
    int cnt = bcnt[b];
    __shared__ int nc[256];
    __shared__ int s[256];
    __shared__ int ncur[256];
    nc[t] = 0;
    __syncthreads();
    for (int e = t; e < cnt; e += 256) atomicAdd(&nc[ebuf[start + e] >> 20], 1);
    __syncthreads();
    int own = nc[t];
    s[t] = own;
    __syncthreads();
    for (int off = 1; off < 256; off <<= 1) {
        int add = (t >= off) ? s[t - off] : 0;
        __syncthreads();
        s[t] += add;
        __syncthreads();
    }
    int rowbase = start + s[t] - own;
    int n0 = b << 8;
    if (n0 + t < N) {
        rowptr[n0 + t] = rowbase;
        dinv[n0 + t] = rsqrtf((float)(own + 1));
    }
    ncur[t] = rowbase;
    __syncthreads();
    for (int e = t; e < cnt; e += 256) {
        int pe = ebuf[start + e];
        int slot = atomicAdd(&ncur[pe >> 20], 1);
        colarr[slot] = pe & 0xFFFFF;
    }
}

// ------- split W [K][N] fp32 -> fp16 hi/lo in MFMA FRAGMENT ORDER -------
__global__ __launch_bounds__(256) void split_wt_frag(const float* __restrict__ W,
                                                     _Float16* __restrict__ hi,
                                                     _Float16* __restrict__ lo,
                                                     int K, int N) {
    int idx = blockIdx.x * 256 + threadIdx.x;
    if (idx >= K * N) return;
    int NT = N >> 4;
    int j = idx & 7;
    int l = (idx >> 3) & 63;
    int f = idx >> 9;
    int nt = f % NT;
    int kc = f / NT;
    int k = kc * 32 + (l >> 4) * 8 + j;
    int n = nt * 16 + (l & 15);
    float v = W[k * N + n];
    _Float16 h = (_Float16)v;
    hi[idx] = h;
    lo[idx] = (_Float16)(v - (float)h);
}

// ---------------- fp16 MFMA GEMM v5: v1 bursts, A dbuf, MFMA-covered loads ----
// Evidence across v1..v4: perf tracks straight-line load-burst size, not
// barriers (v4: ~2 barriers, still 108us) nor occupancy (15-27%, no effect).
// v1 (8x16B cooperative burst per thread, then drain) = 64us; chained
// per-step fragment loads (v2-v4, <=4 deep) = 105-108us. Little's law on
// v4 (0.77 B/cy/CU) -> ~1.5KB in flight/CU: dependency-chained loads defeat
// the compiler's counted-vmcnt batching; straight-line bursts don't.
// v5 = v1's exact burst + MFMA code, but the phase-t+1 A burst ISSUES before
// the phase-t MFMA section and converts AFTER it (A LDS double-buffered,
// +18KB). No barrier ever drains an A load in flight: loads are consumed by
// the cvt before sync#1; sync#2 drains only the L2-hot B asyncs.
//   per phase: AISSUE(t+1) | MFMA(t) | ACVT->Ah[cur^1] | sync | STAGE_B(t+1) | sync
// Worst case (scheduler sinks loads to the cvt) degenerates to v1's 64us.
template <int BN, int KTOT, bool AFP16>
__global__ __launch_bounds__(256, 2) void gemm_f16(const void* __restrict__ Araw,
                                                   const _Float16* __restrict__ Bh_g,
                                                   const _Float16* __restrict__ Bl_g,
                                                   const float* __restrict__ dinv,
                                                   _Float16* __restrict__ C, int M) {
    constexpr int NT = BN / 16;          // 8 (gemm1) / 4 (gemm2)
    constexpr int NPH = KTOT / 64;       // 4 / 2 phases (k-slice 64)
    constexpr int FPW = (2 * NT) / 4;    // B async chunks per wave per table
    __shared__ _Float16 Ah[2][128][72];  // 36.8 KB (double-buffered)
    __shared__ _Float16 Bsh[2 * NT * 512];  // 16 KB / 8 KB (single, per-phase)
    __shared__ _Float16 Bsl[2 * NT * 512];

    const int tid = threadIdx.x;
    const int wave = tid >> 6;
    const int lane = tid & 63;
    const int lm = lane & 15;
    const int q = lane >> 4;
    const int m0 = blockIdx.x * 128;

    const float* Af = (const float*)Araw;
    const _Float16* Ah16 = (const _Float16*)Araw;

    f32x4 acc[2][NT];
#pragma unroll
    for (int a = 0; a < 2; ++a)
#pragma unroll
        for (int b = 0; b < NT; ++b) acc[a][b] = (f32x4){0.f, 0.f, 0.f, 0.f};

    const float4 fz_ = make_float4(0.f, 0.f, 0.f, 0.f);
    const uint4 uz_ = make_uint4(0u, 0u, 0u, 0u);

    // burst registers: 8x float4 (fp32 path, 32 VGPR) or 4x uint4 (fp16 path)
    float4 va[4][2];
    uint4 ua[4];

    // issue the full cooperative A burst for k-slice t_ (straight-line, 8 loads)
#define AISSUE(t_)                                                                \
    do {                                                                          \
        _Pragma("unroll")                                                         \
        for (int i = 0; i < 4; ++i) {                                             \
            int flat = tid + i * 256;                                             \
            int row = flat >> 3;                                                  \
            int kk = (flat & 7) << 3;                                             \
            int gr = m0 + row;                                                    \
            int gk = (t_) * 64 + kk;                                              \
            if (AFP16) {                                                          \
                ua[i] = (gr < M) ? *(const uint4*)&Ah16[(size_t)gr * KTOT + gk]   \
                                 : uz_;                                           \
            } else {                                                              \
                va[i][0] = (gr < M) ? *(const float4*)&Af[(size_t)gr * KTOT + gk] \
                                    : fz_;                                        \
                va[i][1] = (gr < M)                                               \
                               ? *(const float4*)&Af[(size_t)gr * KTOT + gk + 4]  \
                               : fz_;                                             \
            }                                                                     \
        }                                                                         \
    } while (0)

    // convert burst regs -> fp16 -> LDS buffer buf_
#define ACVT(buf_)                                                                \
    do {                                                                          \
        _Pragma("unroll")                                                         \
        for (int i = 0; i < 4; ++i) {                                             \
            int flat = tid + i * 256;                                             \
            int row = flat >> 3;                                                  \
            int kk = (flat & 7) << 3;                                             \
            if (AFP16) {                                                          \
                *(uint4*)&Ah[buf_][row][kk] = ua[i];                              \
            } else {                                                              \
                f16x8 h;                                                          \
                h[0] = (_Float16)va[i][0].x; h[1] = (_Float16)va[i][0].y;         \
                h[2] = (_Float16)va[i][0].z; h[3] = (_Float16)va[i][0].w;         \
                h[4] = (_Float16)va[i][1].x; h[5] = (_Float16)va[i][1].y;         \
                h[6] = (_Float16)va[i][1].z; h[7] = (_Float16)va[i][1].w;         \
                *(f16x8*)&Ah[buf_][row][kk] = h;                                  \
            }                                                                     \
        }                                                                         \
    } while (0)

    // stage phase t_'s B slice (async, L2-hot after first blocks)
#define STAGE_B(t_)                                                               \
    do {                                                                          \
        const int kc0_ = (t_) * 2;                                                \
        const _Float16* bh_ = Bh_g + (size_t)kc0_ * NT * 512;                     \
        const _Float16* bl_ = Bl_g + (size_t)kc0_ * NT * 512;                     \
        _Pragma("unroll")                                                         \
        for (int i = 0; i < FPW; ++i) {                                           \
            int f_ = wave * FPW + i;                                              \
            async_copy16(&Bsh[f_ * 512 + lane * 8], bh_ + f_ * 512 + lane * 8);   \
            async_copy16(&Bsl[f_ * 512 + lane * 8], bl_ + f_ * 512 + lane * 8);   \
        }                                                                         \
    } while (0)

    // prologue: cold-start phase 0 (A burst+cvt, B stage, one drain)
    AISSUE(0);
    ACVT(0);
    STAGE_B(0);
    __syncthreads();

    int cur = 0;
#pragma unroll
    for (int t = 0; t < NPH; ++t) {
        if (t + 1 < NPH) AISSUE(t + 1);   // burst issues; consumed after MFMA

        // ---- MFMA on Ah[cur], Bsh/Bsl (v1 code) ----
#pragma unroll
        for (int dkc = 0; dkc < 2; ++dkc) {
            f16x8 a[2];
#pragma unroll
            for (int mt = 0; mt < 2; ++mt)
                a[mt] = *(const f16x8*)&Ah[cur][wave * 32 + mt * 16 + lm][dkc * 32 + q * 8];
#pragma unroll
            for (int nt = 0; nt < NT; ++nt) {
                f16x8 bh = *(const f16x8*)&Bsh[(dkc * NT + nt) * 512 + lane * 8];
                f16x8 bl = *(const f16x8*)&Bsl[(dkc * NT + nt) * 512 + lane * 8];
#pragma unroll
                for (int mt = 0; mt < 2; ++mt) {
                    acc[mt][nt] = __builtin_amdgcn_mfma_f32_16x16x32_f16(a[mt], bh, acc[mt][nt], 0, 0, 0);
                    acc[mt][nt] = __builtin_amdgcn_mfma_f32_16x16x32_f16(a[mt], bl, acc[mt][nt], 0, 0, 0);
                }
            }
        }

        if (t + 1 < NPH) {
            ACVT(cur ^ 1);        // waits A(t+1) loads (latency covered by MFMA)
            __syncthreads();      // all waves done reading Bsh(t)/Ah[cur]
            STAGE_B(t + 1);       // safe: no readers of Bsh now
            __syncthreads();      // drain B asyncs (L2-hot) + A ds_writes
            cur ^= 1;
        }
    }
#undef AISSUE
#undef ACVT
#undef STAGE_B

#pragma unroll
    for (int mt = 0; mt < 2; ++mt) {
#pragma unroll
        for (int i = 0; i < 4; ++i) {
            int r = m0 + wave * 32 + mt * 16 + q * 4 + i;
            if (r < M) {
                float dv = dinv[r];
#pragma unroll
                for (int nt = 0; nt < NT; ++nt) {
                    C[(size_t)r * BN + nt * 16 + lm] = (_Float16)(acc[mt][nt][i] * dv);
                }
            }
        }
    }
}

// ---------------- aggregation v3: uint4 gathers, masked remainders ----------------
__device__ __forceinline__ void acc8(float* a, uint4 v) {
    float2 f0 = __half22float2(*(const __half2*)&v.x);
    float2 f1 = __half22float2(*(const __half2*)&v.y);
    float2 f2 = __half22float2(*(const __half2*)&v.z);
    float2 f3 = __half22float2(*(const __half2*)&v.w);
    a[0] += f0.x; a[1] += f0.y; a[2] += f1.x; a[3] += f1.y;
    a[4] += f2.x; a[5] += f2.y; a[6] += f3.x; a[7] += f3.y;
}

// 128 ch: wave per node; 4 groups of 16 lanes -> 4 edges per load instruction
// (1 KB/inst). 8 fp16 channels per lane. Butterfly xor16+xor32; sel==0 stores fp16.
__global__ __launch_bounds__(256) void agg128(const _Float16* __restrict__ g,
                                              const int* __restrict__ rowptr,
                                              const int* __restrict__ colarr,
                                              const float* __restrict__ dinv,
                                              const float* __restrict__ bias,
                                              _Float16* __restrict__ out, int n) {
    int node = blockIdx.x * 4 + (threadIdx.x >> 6);
    int lane = threadIdx.x & 63;
    if (node >= n) return;
    int sel = lane >> 4;        // 0..3
    int co = (lane & 15) << 3;  // 8 fp16 channels

    int beg = rowptr[node];
    int end = rowptr[node + 1];

    float a[8] = {0.f, 0.f, 0.f, 0.f, 0.f, 0.f, 0.f, 0.f};
    if (sel == 0) acc8(a, *(const uint4*)&g[(node << 7) + co]);  // self loop

    int p = beg;
    for (; p + 16 <= end; p += 16) {
        int r0 = colarr[p + sel];
        int r1 = colarr[p + 4 + sel];
        int r2 = colarr[p + 8 + sel];
        int r3 = colarr[p + 12 + sel];
        uint4 v0 = *(const uint4*)&g[(r0 << 7) + co];
        uint4 v1 = *(const uint4*)&g[(r1 << 7) + co];
        uint4 v2 = *(const uint4*)&g[(r2 << 7) + co];
        uint4 v3 = *(const uint4*)&g[(r3 << 7) + co];
        acc8(a, v0); acc8(a, v1); acc8(a, v2); acc8(a, v3);
    }
    for (; p + 4 <= end; p += 4) {
        int r = colarr[p + sel];
        acc8(a, *(const uint4*)&g[(r << 7) + co]);
    }
    int rem = end - p;
    if (sel < rem) {
        int r = colarr[p + sel];
        acc8(a, *(const uint4*)&g[(r << 7) + co]);
    }

#pragma unroll
    for (int i = 0; i < 8; ++i) {
        a[i] += __shfl(a[i], lane ^ 16);
        a[i] += __shfl(a[i], lane ^ 32);
    }

    if (sel == 0) {
        float dv = dinv[node];
        float4 b0 = *(const float4*)&bias[co];
        float4 b1 = *(const float4*)&bias[co + 4];
        float o0 = fmaxf(fmaf(a[0], dv, b0.x), 0.f);
        float o1 = fmaxf(fmaf(a[1], dv, b0.y), 0.f);
        float o2 = fmaxf(fmaf(a[2], dv, b0.z), 0.f);
        float o3 = fmaxf(fmaf(a[3], dv, b0.w), 0.f);
        float o4 = fmaxf(fmaf(a[4], dv, b1.x), 0.f);
        float o5 = fmaxf(fmaf(a[5], dv, b1.y), 0.f);
        float o6 = fmaxf(fmaf(a[6], dv, b1.z), 0.f);
        float o7 = fmaxf(fmaf(a[7], dv, b1.w), 0.f);
        __half2 h0 = __floats2half2_rn(o0, o1);
        __half2 h1 = __floats2half2_rn(o2, o3);
        __half2 h2 = __floats2half2_rn(o4, o5);
        __half2 h3 = __floats2half2_rn(o6, o7);
        uint4 pk = make_uint4(*(unsigned*)&h0, *(unsigned*)&h1,
                              *(unsigned*)&h2, *(unsigned*)&h3);
        *(uint4*)&out[(node << 7) + co] = pk;
    }
}

// 64 ch: wave per node; 8 groups of 8 lanes -> 8 edges per load instruction.
// 8 fp16 channels per lane. Butterfly xor8+xor16+xor32; sel==0 stores fp32.
__global__ __launch_bounds__(256) void agg64(const _Float16* __restrict__ g,
                                             const int* __restrict__ rowptr,
                                             const int* __restrict__ colarr,
                                             const float* __restrict__ dinv,
                                             const float* __restrict__ bias,
                                             float* __restrict__ out, int n) {
    int node = blockIdx.x * 4 + (threadIdx.x >> 6);
    int lane = threadIdx.x & 63;
    if (node >= n) return;
    int sel = lane >> 3;       // 0..7
    int co = (lane & 7) << 3;  // 8 fp16 channels

    int beg = rowptr[node];
    int end = rowptr[node + 1];

    float a[8] = {0.f, 0.f, 0.f, 0.f, 0.f, 0.f, 0.f, 0.f};
    if (sel == 0) acc8(a, *(const uint4*)&g[(node << 6) + co]);  // self loop

    int p = beg;
    for (; p + 16 <= end; p += 16) {
        int r0 = colarr[p + sel];
        int r1 = colarr[p + 8 + sel];
        uint4 v0 = *(const uint4*)&g[(r0 << 6) + co];
        uint4 v1 = *(const uint4*)&g[(r1 << 6) + co];
        acc8(a, v0); acc8(a, v1);
    }
    for (; p + 8 <= end; p += 8) {
        int r = colarr[p + sel];
        acc8(a, *(const uint4*)&g[(r << 6) + co]);
    }
    int rem = end - p;
    if (sel < rem) {
        int r = colarr[p + sel];
        acc8(a, *(const uint4*)&g[(r << 6) + co]);
    }

#pragma unroll
    for (int i = 0; i < 8; ++i) {
        a[i] += __shfl(a[i], lane ^ 8);
        a[i] += __shfl(a[i], lane ^ 16);
        a[i] += __shfl(a[i], lane ^ 32);
    }

    if (sel == 0) {
        float dv = dinv[node];
        float4 b0 = *(const float4*)&bias[co];
        float4 b1 = *(const float4*)&bias[co + 4];
        float4 oA, oB;
        oA.x = fmaxf(fmaf(a[0], dv, b0.x), 0.f);
        oA.y = fmaxf(fmaf(a[1], dv, b0.y), 0.f);
        oA.z = fmaxf(fmaf(a[2], dv, b0.z), 0.f);
        oA.w = fmaxf(fmaf(a[3], dv, b0.w), 0.f);
        oB.x = fmaxf(fmaf(a[4], dv, b1.x), 0.f);
        oB.y = fmaxf(fmaf(a[5], dv, b1.y), 0.f);
        oB.z = fmaxf(fmaf(a[6], dv, b1.z), 0.f);
        oB.w = fmaxf(fmaf(a[7], dv, b1.w), 0.f);
        *(float4*)&out[(node << 6) + co] = oA;
        *(float4*)&out[(node << 6) + co + 4] = oB;
    }
}

extern "C" void kernel_launch(void* const* d_in, const int* in_sizes, int n_in,
                              void* d_out, int out_size, void* d_ws, size_t ws_size,
                              hipStream_t stream) {
    const float* x  = (const float*)d_in[0];
    const int*   ei = (const int*)d_in[1];
    const float* W1 = (const float*)d_in[2];
    const float* b1 = (const float*)d_in[3];
    const float* W2 = (const float*)d_in[4];
    const float* b2 = (const float*)d_in[5];
    float* out = (float*)d_out;

    const int E = in_sizes[1] / 2;
    const int H1 = in_sizes[3];                 // 128
    const int K1 = in_sizes[2] / H1;            // 256
    const int N = in_sizes[0] / K1;             // 100000
    const int H2 = in_sizes[4] / H1;            // 64
    const int* src = ei;
    const int* dst = ei + E;
    const int NB = (N + 255) >> 8;

    char* ws = (char*)d_ws;
    _Float16* w1th   = (_Float16*)(ws + OFF_W1TH);
    _Float16* w1tl   = (_Float16*)(ws + OFF_W1TL);
    _Float16* w2th   = (_Float16*)(ws + OFF_W2TH);
    _Float16* w2tl   = (_Float16*)(ws + OFF_W2TL);
    int*      bcnt   = (int*)(ws + OFF_BCNT);
    int*      bbase  = (int*)(ws + OFF_BBASE);
    int*      bcur   = (int*)(ws + OFF_BCUR);
    int*      rowptr = (int*)(ws + OFF_ROWPTR);
    float*    dinv   = (float*)(ws + OFF_DINV);
    int*      colarr = (int*)(ws + OFF_COL);
    int*      ebuf   = (int*)(ws + OFF_EBUF);
    _Float16* h1g    = (_Float16*)(ws + OFF_H1G);
    _Float16* h1out  = (_Float16*)(ws + OFF_H1OUT);
    _Float16* h2g    = (_Float16*)(ws + OFF_H1G);   // reuse

    hipMemsetAsync(bcnt, 0, 512 * sizeof(int), stream);
    bincount<<<256, 256, 0, stream>>>(dst, bcnt, E);
    bscan<<<1, 512, 0, stream>>>(bcnt, bbase, bcur, rowptr, NB, N, E);
    binscatter<<<(E + CHUNK - 1) / CHUNK, 256, 0, stream>>>(src, dst, bcur, ebuf, E);
    buildcsr<<<NB, 256, 0, stream>>>(ebuf, bbase, bcnt, rowptr, colarr, dinv, N);

    split_wt_frag<<<(K1 * H1 + 255) / 256, 256, 0, stream>>>(W1, w1th, w1tl, K1, H1);
    split_wt_frag<<<(H1 * H2 + 255) / 256, 256, 0, stream>>>(W2, w2th, w2tl, H1, H2);

    // layer 1
    gemm_f16<128, 256, false><<<(N + 127) / 128, 256, 0, stream>>>(x, w1th, w1tl, dinv, h1g, N);
    agg128<<<(N + 3) / 4, 256, 0, stream>>>(h1g, rowptr, colarr, dinv, b1, h1out, N);

    // layer 2
    gemm_f16<64, 128, true><<<(N + 127) / 128, 256, 0, stream>>>(h1out, w2th, w2tl, dinv, h2g, N);
    agg64<<<(N + 3) / 4, 256, 0, stream>>>(h2g, rowptr, colarr, dinv, b2, out, N);
}

// Round 7
// 391.621 us; speedup vs baseline: 1.0826x; 1.0826x over previous
//
#include <hip/hip_runtime.h>
#include <hip/hip_fp16.h>

// ---------------- problem constants ----------------
#define NNODES 100000

// ---------------- workspace layout (bytes) ----------------
#define OFF_W1TH     0UL            // _Float16[256*128] frag-order = 65536
#define OFF_W1TL     65536UL        // _Float16[256*128]
#define OFF_W2TH     131072UL       // _Float16[128*64] = 16384
#define OFF_W2TL     147456UL       // _Float16[128*64] -> ends 163840
#define OFF_BCNT     163840UL       // int[512]
#define OFF_BBASE    165888UL       // int[512]
#define OFF_BCUR     167936UL       // int[512] -> ends 169984
#define OFF_ROWPTR   400128UL       // int[100001]
#define OFF_DINV     1200640UL      // float[100000]
#define OFF_COL      1605632UL      // int[1600000]  -> ends 8005632
#define OFF_EBUF     8005632UL      // int[1600000] = 6.4MB (overlaps h1g; dead before gemm1)
#define OFF_H1G      8005632UL      // half[100000*128] = 25.6MB -> ends 33605632
#define OFF_H1OUT    59205632UL     // half[100000*128] = 25.6MB -> ends 84805632
// h2g (half[100000*64]) reuses OFF_H1G (h1g dead after agg1)

typedef __attribute__((ext_vector_type(8))) _Float16 f16x8;
typedef __attribute__((ext_vector_type(4))) float f32x4;

// async global->LDS 16B per lane (dest = wave-uniform base + lane*16)
__device__ __forceinline__ void async_copy16(void* lds, const void* g) {
    __builtin_amdgcn_global_load_lds(
        (const __attribute__((address_space(1))) unsigned*)g,
        (__attribute__((address_space(3))) unsigned*)lds, 16, 0, 0);
}

// =========== CSR build via 2-level counting sort (bucket = dst>>8) ===========
__global__ __launch_bounds__(256) void bincount(const int* __restrict__ dst,
                                                int* __restrict__ bcnt, int E) {
    __shared__ int lc[512];
    int t = threadIdx.x;
    lc[t] = 0; lc[t + 256] = 0;
    __syncthreads();
    for (int e = blockIdx.x * 256 + t; e < E; e += gridDim.x * 256)
        atomicAdd(&lc[dst[e] >> 8], 1);
    __syncthreads();
    if (lc[t]) atomicAdd(&bcnt[t], lc[t]);
    if (lc[t + 256]) atomicAdd(&bcnt[t + 256], lc[t + 256]);
}

__global__ __launch_bounds__(512) void bscan(const int* __restrict__ bcnt,
                                             int* __restrict__ bbase,
                                             int* __restrict__ bcur,
                                             int* __restrict__ rowptr,
                                             int NB, int N, int E) {
    __shared__ int s[512];
    int t = threadIdx.x;
    int v = (t < NB) ? bcnt[t] : 0;
    s[t] = v;
    __syncthreads();
    for (int off = 1; off < 512; off <<= 1) {
        int add = (t >= off) ? s[t - off] : 0;
        __syncthreads();
        s[t] += add;
        __syncthreads();
    }
    if (t < NB) {
        int ex = s[t] - v;
        bbase[t] = ex;
        bcur[t] = ex;
    }
    if (t == 0) rowptr[N] = E;
}

// Phase C: bucket-grouped scatter. Packs (src | localdst<<20) into one int.
#define CHUNK 8192
__global__ __launch_bounds__(256) void binscatter(const int* __restrict__ src,
                                                  const int* __restrict__ dst,
                                                  int* __restrict__ bcur,
                                                  int* __restrict__ ebuf, int E) {
    __shared__ int lc[512];
    __shared__ int gb[512];
    int t = threadIdx.x;
    lc[t] = 0; lc[t + 256] = 0;
    __syncthreads();
    int base = blockIdx.x * CHUNK;
    int rb[32];
#pragma unroll
    for (int i = 0; i < 32; ++i) {
        int e = base + i * 256 + t;
        if (e < E) {
            int b = dst[e] >> 8;
            rb[i] = (b << 13) | atomicAdd(&lc[b], 1);  // rank < 8192 fits 13 bits
        } else rb[i] = -1;
    }
    __syncthreads();
    if (lc[t]) gb[t] = atomicAdd(&bcur[t], lc[t]);
    if (lc[t + 256]) gb[t + 256] = atomicAdd(&bcur[t + 256], lc[t + 256]);
    __syncthreads();
#pragma unroll
    for (int i = 0; i < 32; ++i) {
        if (rb[i] >= 0) {
            int e = base + i * 256 + t;
            int b = rb[i] >> 13, r = rb[i] & 8191;
            ebuf[gb[b] + r] = src[e] | ((dst[e] & 255) << 20);
        }
    }
}

__global__ __launch_bounds__(256) void buildcsr(const int* __restrict__ ebuf,
                                                const int* __restrict__ bbase,
                                                const int* __restrict__ bcnt,
                                                int* __restrict__ rowptr,
                                                int* __restrict__ colarr,
                                                float* __restrict__ dinv, int N) {
    int b = blockIdx.x;
    int t = threadIdx.x;
    int start = bbase[b];
    int cnt = bcnt[b];
    __shared__ int nc[256];
    __shared__ int s[256];
    __shared__ int ncur[256];
    nc[t] = 0;
    __syncthreads();
    for (int e = t; e < cnt; e += 256) atomicAdd(&nc[ebuf[start + e] >> 20], 1);
    __syncthreads();
    int own = nc[t];
    s[t] = own;
    __syncthreads();
    for (int off = 1; off < 256; off <<= 1) {
        int add = (t >= off) ? s[t - off] : 0;
        __syncthreads();
        s[t] += add;
        __syncthreads();
    }
    int rowbase = start + s[t] - own;
    int n0 = b << 8;
    if (n0 + t < N) {
        rowptr[n0 + t] = rowbase;
        dinv[n0 + t] = rsqrtf((float)(own + 1));
    }
    ncur[t] = rowbase;
    __syncthreads();
    for (int e = t; e < cnt; e += 256) {
        int pe = ebuf[start + e];
        int slot = atomicAdd(&ncur[pe >> 20], 1);
        colarr[slot] = pe & 0xFFFFF;
    }
}

// ------- split W [K][N] fp32 -> fp16 hi/lo in MFMA FRAGMENT ORDER -------
__global__ __launch_bounds__(256) void split_wt_frag(const float* __restrict__ W,
                                                     _Float16* __restrict__ hi,
                                                     _Float16* __restrict__ lo,
                                                     int K, int N) {
    int idx = blockIdx.x * 256 + threadIdx.x;
    if (idx >= K * N) return;
    int NT = N >> 4;
    int j = idx & 7;
    int l = (idx >> 3) & 63;
    int f = idx >> 9;
    int nt = f % NT;
    int kc = f / NT;
    int k = kc * 32 + (l >> 4) * 8 + j;
    int n = nt * 16 + (l & 15);
    float v = W[k * N + n];
    _Float16 h = (_Float16)v;
    hi[idx] = h;
    lo[idx] = (_Float16)(v - (float)h);
}

// -------- fp16 MFMA GEMM v6c: full-row A resident, contiguous single read -----
// v1-v5 post-mortem: ALL variants k-phased the A tile, so each phase read 256B
// out of every 1KB row (25% duty strided sweep over 102MB, repeated 4x).
// Effective read BW stuck at ~1.6 TB/s regardless of pipeline/barrier/burst
// scheduling -> the access PATTERN, not the schedule, is the limiter.
// v6: stage the FULL-K A tile once per block, contiguously; every byte of x
// read exactly once, sequentially. B cycles through a double buffer staged
// async under the previous phase's MFMA; one barrier per phase.
// v6->v6b: fixed fp16-stage row-wrap (hard-coded 256-half rows).
// v6b->v6c: the fp16 stage had a SECOND bug — 64-half slots but only 4xuint4
// = 32 halves loaded, leaving halves 32..63 of every slot stale (absmax 1855).
// Fix: slot size = load size: TPR = KTOT/32 (32 halves/thread, exactly 4
// uint4), NIT = 128*TPR/256. fp32 path (gemm1) always had matching geometry.
template <int BN, int KTOT, bool AFP16>
__global__ __launch_bounds__(256) void gemm_f16(const void* __restrict__ Araw,
                                                const _Float16* __restrict__ Bh_g,
                                                const _Float16* __restrict__ Bl_g,
                                                const float* __restrict__ dinv,
                                                _Float16* __restrict__ C, int M) {
    constexpr int NT = BN / 16;             // 8 (gemm1) / 4 (gemm2)
    constexpr int NKC = KTOT / 32;          // 8 / 4 k-chunks
    constexpr int KCPP = AFP16 ? NKC : 2;   // k-chunks per B-phase: all / 2
    constexpr int NPH = NKC / KCPP;         // 1 / 4 phases
    constexpr int KPAD = KTOT + 8;          // fp16 row stride (pad: 2-way banks)
    constexpr int BTILE = KCPP * NT * 512;  // halves per B slice = 8192 both
    constexpr int NBUF = (NPH > 1) ? 2 : 1;
    __shared__ _Float16 Ah[128 * KPAD];     // 67.6KB / 34.8KB
    __shared__ _Float16 Bsh[NBUF * BTILE];  // 32KB / 16KB
    __shared__ _Float16 Bsl[NBUF * BTILE];

    const int tid = threadIdx.x;
    const int wave = tid >> 6;
    const int lane = tid & 63;
    const int lm = lane & 15;
    const int q = lane >> 4;
    const int m0 = blockIdx.x * 128;

#define STAGE_B(ph_, b_)                                                          \
    do {                                                                          \
        _Pragma("unroll")                                                         \
        for (int c_ = 0; c_ < 4; ++c_) {                                          \
            int off_ = (c_ * 256 + tid) * 8;                                      \
            async_copy16(&Bsh[(b_) * BTILE + off_],                               \
                         Bh_g + (size_t)(ph_) * BTILE + off_);                    \
            async_copy16(&Bsl[(b_) * BTILE + off_],                               \
                         Bl_g + (size_t)(ph_) * BTILE + off_);                    \
        }                                                                         \
    } while (0)

    // B slice 0 in flight while we stream A
    STAGE_B(0, 0);

    // ---- A-stage: full-K rows, contiguous, read-once ----
    if (AFP16) {
        const _Float16* A16 = (const _Float16*)Araw;
        constexpr int TPR = KTOT / 32;              // threads per row (32 halves each)
        constexpr int NIT = (128 * TPR) / 256;      // staging iterations
#pragma unroll
        for (int i = 0; i < NIT; ++i) {
            int flat = i * 256 + tid;
            int row = flat / TPR;
            int c0 = (flat % TPR) * 32;             // halves; 32 halves = 4x uint4
            int gr = m0 + row;
            uint4 u0 = make_uint4(0u,0u,0u,0u), u1 = u0, u2 = u0, u3 = u0;
            if (gr < M) {
                const uint4* p = (const uint4*)&A16[(size_t)gr * KTOT + c0];
                u0 = p[0]; u1 = p[1]; u2 = p[2]; u3 = p[3];
            }
            uint4* d = (uint4*)&Ah[row * KPAD + c0];
            d[0] = u0; d[1] = u1; d[2] = u2; d[3] = u3;
        }
    } else {
        const float* Af = (const float*)Araw;
        constexpr int TPR = KTOT / 32;              // threads per row (32 floats each)
        constexpr int NIT = (128 * TPR) / 256;      // staging iterations
#pragma unroll
        for (int i = 0; i < NIT; ++i) {
            int flat = i * 256 + tid;
            int row = flat / TPR;
            int c0 = (flat % TPR) * 32;             // floats (== halves in dest)
            int gr = m0 + row;
            float4 v0 = make_float4(0.f,0.f,0.f,0.f);
            float4 v1 = v0, v2 = v0, v3 = v0, v4 = v0, v5 = v0, v6 = v0, v7 = v0;
            if (gr < M) {
                const float4* p = (const float4*)&Af[(size_t)gr * KTOT + c0];
                v0 = p[0]; v1 = p[1]; v2 = p[2]; v3 = p[3];
                v4 = p[4]; v5 = p[5]; v6 = p[6]; v7 = p[7];
            }
            f16x8 h0, h1, h2, h3;
            h0[0]=(_Float16)v0.x; h0[1]=(_Float16)v0.y; h0[2]=(_Float16)v0.z; h0[3]=(_Float16)v0.w;
            h0[4]=(_Float16)v1.x; h0[5]=(_Float16)v1.y; h0[6]=(_Float16)v1.z; h0[7]=(_Float16)v1.w;
            h1[0]=(_Float16)v2.x; h1[1]=(_Float16)v2.y; h1[2]=(_Float16)v2.z; h1[3]=(_Float16)v2.w;
            h1[4]=(_Float16)v3.x; h1[5]=(_Float16)v3.y; h1[6]=(_Float16)v3.z; h1[7]=(_Float16)v3.w;
            h2[0]=(_Float16)v4.x; h2[1]=(_Float16)v4.y; h2[2]=(_Float16)v4.z; h2[3]=(_Float16)v4.w;
            h2[4]=(_Float16)v5.x; h2[5]=(_Float16)v5.y; h2[6]=(_Float16)v5.z; h2[7]=(_Float16)v5.w;
            h3[0]=(_Float16)v6.x; h3[1]=(_Float16)v6.y; h3[2]=(_Float16)v6.z; h3[3]=(_Float16)v6.w;
            h3[4]=(_Float16)v7.x; h3[5]=(_Float16)v7.y; h3[6]=(_Float16)v7.z; h3[7]=(_Float16)v7.w;
            _Float16* d = &Ah[row * KPAD + c0];
            *(f16x8*)&d[0]  = h0;
            *(f16x8*)&d[8]  = h1;
            *(f16x8*)&d[16] = h2;
            *(f16x8*)&d[24] = h3;
        }
    }
    __syncthreads();  // A resident + B slice 0 drained

    f32x4 acc[2][NT];
#pragma unroll
    for (int a = 0; a < 2; ++a)
#pragma unroll
        for (int b = 0; b < NT; ++b) acc[a][b] = (f32x4){0.f, 0.f, 0.f, 0.f};

    int bufo = 0;
#pragma unroll
    for (int ph = 0; ph < NPH; ++ph) {
        if (NPH > 1 && ph + 1 < NPH) STAGE_B(ph + 1, bufo ^ 1);  // hidden by MFMA

#pragma unroll
        for (int dkc = 0; dkc < KCPP; ++dkc) {
            const int kc = ph * KCPP + dkc;
            f16x8 a[2];
#pragma unroll
            for (int mt = 0; mt < 2; ++mt)
                a[mt] = *(const f16x8*)&Ah[(wave * 32 + mt * 16 + lm) * KPAD + kc * 32 + q * 8];
#pragma unroll
            for (int nt = 0; nt < NT; ++nt) {
                f16x8 bh = *(const f16x8*)&Bsh[bufo * BTILE + (dkc * NT + nt) * 512 + lane * 8];
                f16x8 bl = *(const f16x8*)&Bsl[bufo * BTILE + (dkc * NT + nt) * 512 + lane * 8];
#pragma unroll
                for (int mt = 0; mt < 2; ++mt) {
                    acc[mt][nt] = __builtin_amdgcn_mfma_f32_16x16x32_f16(a[mt], bh, acc[mt][nt], 0, 0, 0);
                    acc[mt][nt] = __builtin_amdgcn_mfma_f32_16x16x32_f16(a[mt], bl, acc[mt][nt], 0, 0, 0);
                }
            }
        }
        if (ph + 1 < NPH) {  // drain next-slice asyncs; guard buffer reuse
            __syncthreads();
            bufo ^= 1;
        }
    }
#undef STAGE_B

#pragma unroll
    for (int mt = 0; mt < 2; ++mt) {
#pragma unroll
        for (int i = 0; i < 4; ++i) {
            int r = m0 + wave * 32 + mt * 16 + q * 4 + i;
            if (r < M) {
                float dv = dinv[r];
#pragma unroll
                for (int nt = 0; nt < NT; ++nt) {
                    C[(size_t)r * BN + nt * 16 + lm] = (_Float16)(acc[mt][nt][i] * dv);
                }
            }
        }
    }
}

// ---------------- aggregation v3: uint4 gathers, masked remainders ----------------
__device__ __forceinline__ void acc8(float* a, uint4 v) {
    float2 f0 = __half22float2(*(const __half2*)&v.x);
    float2 f1 = __half22float2(*(const __half2*)&v.y);
    float2 f2 = __half22float2(*(const __half2*)&v.z);
    float2 f3 = __half22float2(*(const __half2*)&v.w);
    a[0] += f0.x; a[1] += f0.y; a[2] += f1.x; a[3] += f1.y;
    a[4] += f2.x; a[5] += f2.y; a[6] += f3.x; a[7] += f3.y;
}

// 128 ch: wave per node; 4 groups of 16 lanes -> 4 edges per load instruction
// (1 KB/inst). 8 fp16 channels per lane. Butterfly xor16+xor32; sel==0 stores fp16.
__global__ __launch_bounds__(256) void agg128(const _Float16* __restrict__ g,
                                              const int* __restrict__ rowptr,
                                              const int* __restrict__ colarr,
                                              const float* __restrict__ dinv,
                                              const float* __restrict__ bias,
                                              _Float16* __restrict__ out, int n) {
    int node = blockIdx.x * 4 + (threadIdx.x >> 6);
    int lane = threadIdx.x & 63;
    if (node >= n) return;
    int sel = lane >> 4;        // 0..3
    int co = (lane & 15) << 3;  // 8 fp16 channels

    int beg = rowptr[node];
    int end = rowptr[node + 1];

    float a[8] = {0.f, 0.f, 0.f, 0.f, 0.f, 0.f, 0.f, 0.f};
    if (sel == 0) acc8(a, *(const uint4*)&g[(node << 7) + co]);  // self loop

    int p = beg;
    for (; p + 16 <= end; p += 16) {
        int r0 = colarr[p + sel];
        int r1 = colarr[p + 4 + sel];
        int r2 = colarr[p + 8 + sel];
        int r3 = colarr[p + 12 + sel];
        uint4 v0 = *(const uint4*)&g[(r0 << 7) + co];
        uint4 v1 = *(const uint4*)&g[(r1 << 7) + co];
        uint4 v2 = *(const uint4*)&g[(r2 << 7) + co];
        uint4 v3 = *(const uint4*)&g[(r3 << 7) + co];
        acc8(a, v0); acc8(a, v1); acc8(a, v2); acc8(a, v3);
    }
    for (; p + 4 <= end; p += 4) {
        int r = colarr[p + sel];
        acc8(a, *(const uint4*)&g[(r << 7) + co]);
    }
    int rem = end - p;
    if (sel < rem) {
        int r = colarr[p + sel];
        acc8(a, *(const uint4*)&g[(r << 7) + co]);
    }

#pragma unroll
    for (int i = 0; i < 8; ++i) {
        a[i] += __shfl(a[i], lane ^ 16);
        a[i] += __shfl(a[i], lane ^ 32);
    }

    if (sel == 0) {
        float dv = dinv[node];
        float4 b0 = *(const float4*)&bias[co];
        float4 b1 = *(const float4*)&bias[co + 4];
        float o0 = fmaxf(fmaf(a[0], dv, b0.x), 0.f);
        float o1 = fmaxf(fmaf(a[1], dv, b0.y), 0.f);
        float o2 = fmaxf(fmaf(a[2], dv, b0.z), 0.f);
        float o3 = fmaxf(fmaf(a[3], dv, b0.w), 0.f);
        float o4 = fmaxf(fmaf(a[4], dv, b1.x), 0.f);
        float o5 = fmaxf(fmaf(a[5], dv, b1.y), 0.f);
        float o6 = fmaxf(fmaf(a[6], dv, b1.z), 0.f);
        float o7 = fmaxf(fmaf(a[7], dv, b1.w), 0.f);
        __half2 h0 = __floats2half2_rn(o0, o1);
        __half2 h1 = __floats2half2_rn(o2, o3);
        __half2 h2 = __floats2half2_rn(o4, o5);
        __half2 h3 = __floats2half2_rn(o6, o7);
        uint4 pk = make_uint4(*(unsigned*)&h0, *(unsigned*)&h1,
                              *(unsigned*)&h2, *(unsigned*)&h3);
        *(uint4*)&out[(node << 7) + co] = pk;
    }
}

// 64 ch: wave per node; 8 groups of 8 lanes -> 8 edges per load instruction.
// 8 fp16 channels per lane. Butterfly xor8+xor16+xor32; sel==0 stores fp32.
__global__ __launch_bounds__(256) void agg64(const _Float16* __restrict__ g,
                                             const int* __restrict__ rowptr,
                                             const int* __restrict__ colarr,
                                             const float* __restrict__ dinv,
                                             const float* __restrict__ bias,
                                             float* __restrict__ out, int n) {
    int node = blockIdx.x * 4 + (threadIdx.x >> 6);
    int lane = threadIdx.x & 63;
    if (node >= n) return;
    int sel = lane >> 3;       // 0..7
    int co = (lane & 7) << 3;  // 8 fp16 channels

    int beg = rowptr[node];
    int end = rowptr[node + 1];

    float a[8] = {0.f, 0.f, 0.f, 0.f, 0.f, 0.f, 0.f, 0.f};
    if (sel == 0) acc8(a, *(const uint4*)&g[(node << 6) + co]);  // self loop

    int p = beg;
    for (; p + 16 <= end; p += 16) {
        int r0 = colarr[p + sel];
        int r1 = colarr[p + 8 + sel];
        uint4 v0 = *(const uint4*)&g[(r0 << 6) + co];
        uint4 v1 = *(const uint4*)&g[(r1 << 6) + co];
        acc8(a, v0); acc8(a, v1);
    }
    for (; p + 8 <= end; p += 8) {
        int r = colarr[p + sel];
        acc8(a, *(const uint4*)&g[(r << 6) + co]);
    }
    int rem = end - p;
    if (sel < rem) {
        int r = colarr[p + sel];
        acc8(a, *(const uint4*)&g[(r << 6) + co]);
    }

#pragma unroll
    for (int i = 0; i < 8; ++i) {
        a[i] += __shfl(a[i], lane ^ 8);
        a[i] += __shfl(a[i], lane ^ 16);
        a[i] += __shfl(a[i], lane ^ 32);
    }

    if (sel == 0) {
        float dv = dinv[node];
        float4 b0 = *(const float4*)&bias[co];
        float4 b1 = *(const float4*)&bias[co + 4];
        float4 oA, oB;
        oA.x = fmaxf(fmaf(a[0], dv, b0.x), 0.f);
        oA.y = fmaxf(fmaf(a[1], dv, b0.y), 0.f);
        oA.z = fmaxf(fmaf(a[2], dv, b0.z), 0.f);
        oA.w = fmaxf(fmaf(a[3], dv, b0.w), 0.f);
        oB.x = fmaxf(fmaf(a[4], dv, b1.x), 0.f);
        oB.y = fmaxf(fmaf(a[5], dv, b1.y), 0.f);
        oB.z = fmaxf(fmaf(a[6], dv, b1.z), 0.f);
        oB.w = fmaxf(fmaf(a[7], dv, b1.w), 0.f);
        *(float4*)&out[(node << 6) + co] = oA;
        *(float4*)&out[(node << 6) + co + 4] = oB;
    }
}

extern "C" void kernel_launch(void* const* d_in, const int* in_sizes, int n_in,
                              void* d_out, int out_size, void* d_ws, size_t ws_size,
                              hipStream_t stream) {
    const float* x  = (const float*)d_in[0];
    const int*   ei = (const int*)d_in[1];
    const float* W1 = (const float*)d_in[2];
    const float* b1 = (const float*)d_in[3];
    const float* W2 = (const float*)d_in[4];
    const float* b2 = (const float*)d_in[5];
    float* out = (float*)d_out;

    const int E = in_sizes[1] / 2;
    const int H1 = in_sizes[3];                 // 128
    const int K1 = in_sizes[2] / H1;            // 256
    const int N = in_sizes[0] / K1;             // 100000
    const int H2 = in_sizes[4] / H1;            // 64
    const int* src = ei;
    const int* dst = ei + E;
    const int NB = (N + 255) >> 8;

    char* ws = (char*)d_ws;
    _Float16* w1th   = (_Float16*)(ws + OFF_W1TH);
    _Float16* w1tl   = (_Float16*)(ws + OFF_W1TL);
    _Float16* w2th   = (_Float16*)(ws + OFF_W2TH);
    _Float16* w2tl   = (_Float16*)(ws + OFF_W2TL);
    int*      bcnt   = (int*)(ws + OFF_BCNT);
    int*      bbase  = (int*)(ws + OFF_BBASE);
    int*      bcur   = (int*)(ws + OFF_BCUR);
    int*      rowptr = (int*)(ws + OFF_ROWPTR);
    float*    dinv   = (float*)(ws + OFF_DINV);
    int*      colarr = (int*)(ws + OFF_COL);
    int*      ebuf   = (int*)(ws + OFF_EBUF);
    _Float16* h1g    = (_Float16*)(ws + OFF_H1G);
    _Float16* h1out  = (_Float16*)(ws + OFF_H1OUT);
    _Float16* h2g    = (_Float16*)(ws + OFF_H1G);   // reuse

    hipMemsetAsync(bcnt, 0, 512 * sizeof(int), stream);
    bincount<<<256, 256, 0, stream>>>(dst, bcnt, E);
    bscan<<<1, 512, 0, stream>>>(bcnt, bbase, bcur, rowptr, NB, N, E);
    binscatter<<<(E + CHUNK - 1) / CHUNK, 256, 0, stream>>>(src, dst, bcur, ebuf, E);
    buildcsr<<<NB, 256, 0, stream>>>(ebuf, bbase, bcnt, rowptr, colarr, dinv, N);

    split_wt_frag<<<(K1 * H1 + 255) / 256, 256, 0, stream>>>(W1, w1th, w1tl, K1, H1);
    split_wt_frag<<<(H1 * H2 + 255) / 256, 256, 0, stream>>>(W2, w2th, w2tl, H1, H2);

    // layer 1
    gemm_f16<128, 256, false><<<(N + 127) / 128, 256, 0, stream>>>(x, w1th, w1tl, dinv, h1g, N);
    agg128<<<(N + 3) / 4, 256, 0, stream>>>(h1g, rowptr, colarr, dinv, b1, h1out, N);

    // layer 2
    gemm_f16<64, 128, true><<<(N + 127) / 128, 256, 0, stream>>>(h1out, w2th, w2tl, dinv, h2g, N);
    agg64<<<(N + 3) / 4, 256, 0, stream>>>(h2g, rowptr, colarr, dinv, b2, out, N);
}

// Round 8
// 386.999 us; speedup vs baseline: 1.0955x; 1.0119x over previous
//
#include <hip/hip_runtime.h>
#include <hip/hip_fp16.h>

// ---------------- problem constants ----------------
#define NNODES 100000

// ---------------- workspace layout (bytes) ----------------
#define OFF_W1TH     0UL            // _Float16[256*128] frag-order = 65536
#define OFF_W1TL     65536UL        // _Float16[256*128]
#define OFF_W2TH     131072UL       // _Float16[128*64] = 16384
#define OFF_W2TL     147456UL       // _Float16[128*64] -> ends 163840
#define OFF_BCNT     163840UL       // int[512]
#define OFF_BBASE    165888UL       // int[512]
#define OFF_BCUR     167936UL       // int[512] -> ends 169984
#define OFF_ROWPTR   400128UL       // int[100001]
#define OFF_DINV     1200640UL      // float[100000]
#define OFF_COL      1605632UL      // int[1600000]  -> ends 8005632
#define OFF_EBUF     8005632UL      // int[1600000] = 6.4MB (overlaps h1g; dead before gemm1)
#define OFF_H1G      8005632UL      // half[100000*128] = 25.6MB -> ends 33605632
#define OFF_H1OUT    59205632UL     // half[100000*128] = 25.6MB -> ends 84805632
// h2g (half[100000*64]) reuses OFF_H1G (h1g dead after agg1)

typedef __attribute__((ext_vector_type(8))) _Float16 f16x8;
typedef __attribute__((ext_vector_type(4))) float f32x4;

// async global->LDS 16B per lane (dest = wave-uniform base + lane*16)
__device__ __forceinline__ void async_copy16(void* lds, const void* g) {
    __builtin_amdgcn_global_load_lds(
        (const __attribute__((address_space(1))) unsigned*)g,
        (__attribute__((address_space(3))) unsigned*)lds, 16, 0, 0);
}

// =========== CSR build via 2-level counting sort (bucket = dst>>8) ===========
__global__ __launch_bounds__(256) void bincount(const int* __restrict__ dst,
                                                int* __restrict__ bcnt, int E) {
    __shared__ int lc[512];
    int t = threadIdx.x;
    lc[t] = 0; lc[t + 256] = 0;
    __syncthreads();
    for (int e = blockIdx.x * 256 + t; e < E; e += gridDim.x * 256)
        atomicAdd(&lc[dst[e] >> 8], 1);
    __syncthreads();
    if (lc[t]) atomicAdd(&bcnt[t], lc[t]);
    if (lc[t + 256]) atomicAdd(&bcnt[t + 256], lc[t + 256]);
}

__global__ __launch_bounds__(512) void bscan(const int* __restrict__ bcnt,
                                             int* __restrict__ bbase,
                                             int* __restrict__ bcur,
                                             int* __restrict__ rowptr,
                                             int NB, int N, int E) {
    __shared__ int s[512];
    int t = threadIdx.x;
    int v = (t < NB) ? bcnt[t] : 0;
    s[t] = v;
    __syncthreads();
    for (int off = 1; off < 512; off <<= 1) {
        int add = (t >= off) ? s[t - off] : 0;
        __syncthreads();
        s[t] += add;
        __syncthreads();
    }
    if (t < NB) {
        int ex = s[t] - v;
        bbase[t] = ex;
        bcur[t] = ex;
    }
    if (t == 0) rowptr[N] = E;
}

// Phase C: bucket-grouped scatter. Packs (src | localdst<<20) into one int.
#define CHUNK 8192
__global__ __launch_bounds__(256) void binscatter(const int* __restrict__ src,
                                                  const int* __restrict__ dst,
                                                  int* __restrict__ bcur,
                                                  int* __restrict__ ebuf, int E) {
    __shared__ int lc[512];
    __shared__ int gb[512];
    int t = threadIdx.x;
    lc[t] = 0; lc[t + 256] = 0;
    __syncthreads();
    int base = blockIdx.x * CHUNK;
    int rb[32];
#pragma unroll
    for (int i = 0; i < 32; ++i) {
        int e = base + i * 256 + t;
        if (e < E) {
            int b = dst[e] >> 8;
            rb[i] = (b << 13) | atomicAdd(&lc[b], 1);  // rank < 8192 fits 13 bits
        } else rb[i] = -1;
    }
    __syncthreads();
    if (lc[t]) gb[t] = atomicAdd(&bcur[t], lc[t]);
    if (lc[t + 256]) gb[t + 256] = atomicAdd(&bcur[t + 256], lc[t + 256]);
    __syncthreads();
#pragma unroll
    for (int i = 0; i < 32; ++i) {
        if (rb[i] >= 0) {
            int e = base + i * 256 + t;
            int b = rb[i] >> 13, r = rb[i] & 8191;
            ebuf[gb[b] + r] = src[e] | ((dst[e] & 255) << 20);
        }
    }
}

__global__ __launch_bounds__(256) void buildcsr(const int* __restrict__ ebuf,
                                                const int* __restrict__ bbase,
                                                const int* __restrict__ bcnt,
                                                int* __restrict__ rowptr,
                                                int* __restrict__ colarr,
                                                float* __restrict__ dinv, int N) {
    int b = blockIdx.x;
    int t = threadIdx.x;
    int start = bbase[b];
    int cnt = bcnt[b];
    __shared__ int nc[256];
    __shared__ int s[256];
    __shared__ int ncur[256];
    nc[t] = 0;
    __syncthreads();
    for (int e = t; e < cnt; e += 256) atomicAdd(&nc[ebuf[start + e] >> 20], 1);
    __syncthreads();
    int own = nc[t];
    s[t] = own;
    __syncthreads();
    for (int off = 1; off < 256; off <<= 1) {
        int add = (t >= off) ? s[t - off] : 0;
        __syncthreads();
        s[t] += add;
        __syncthreads();
    }
    int rowbase = start + s[t] - own;
    int n0 = b << 8;
    if (n0 + t < N) {
        rowptr[n0 + t] = rowbase;
        dinv[n0 + t] = rsqrtf((float)(own + 1));
    }
    ncur[t] = rowbase;
    __syncthreads();
    for (int e = t; e < cnt; e += 256) {
        int pe = ebuf[start + e];
        int slot = atomicAdd(&ncur[pe >> 20], 1);
        colarr[slot] = pe & 0xFFFFF;
    }
}

// ------- split W [K][N] fp32 -> fp16 hi/lo in MFMA FRAGMENT ORDER -------
__global__ __launch_bounds__(256) void split_wt_frag(const float* __restrict__ W,
                                                     _Float16* __restrict__ hi,
                                                     _Float16* __restrict__ lo,
                                                     int K, int N) {
    int idx = blockIdx.x * 256 + threadIdx.x;
    if (idx >= K * N) return;
    int NT = N >> 4;
    int j = idx & 7;
    int l = (idx >> 3) & 63;
    int f = idx >> 9;
    int nt = f % NT;
    int kc = f / NT;
    int k = kc * 32 + (l >> 4) * 8 + j;
    int n = nt * 16 + (l & 15);
    float v = W[k * N + n];
    _Float16 h = (_Float16)v;
    hi[idx] = h;
    lo[idx] = (_Float16)(v - (float)h);
}

// ---------------- fp16 MFMA GEMM (round-0 form — best measured: 64us) ---------
// GEMM history: six structural rewrites (A-direct-to-reg pipeline, barrier-free
// B-stationary, dbuf'd bursts, full-row-resident A) all measured 64-110us; this
// round-0 form remains the floor. Verdict: its limiter is not barriers, not
// occupancy, not A access pattern; FETCH shows L2/L3 already absorb half the
// x-reads. Frozen per round-7 pre-commitment.
template <int BN, int KTOT, bool AFP16>
__global__ __launch_bounds__(256, 3) void gemm_f16(const void* __restrict__ Araw,
                                                   const _Float16* __restrict__ Bh_g,
                                                   const _Float16* __restrict__ Bl_g,
                                                   const float* __restrict__ dinv,
                                                   _Float16* __restrict__ C, int M) {
    constexpr int NT = BN / 16;
    constexpr int FPW = (2 * NT) / 4;
    __shared__ _Float16 Ah[128][72];
    __shared__ _Float16 Bsh[2 * NT * 512];
    __shared__ _Float16 Bsl[2 * NT * 512];

    const int tid = threadIdx.x;
    const int wave = tid >> 6;
    const int lane = tid & 63;
    const int lm = lane & 15;
    const int q = lane >> 4;
    const int m0 = blockIdx.x * 128;

    f32x4 acc[2][NT];
#pragma unroll
    for (int a = 0; a < 2; ++a)
#pragma unroll
        for (int b = 0; b < NT; ++b) acc[a][b] = (f32x4){0.f, 0.f, 0.f, 0.f};

    for (int k0 = 0; k0 < KTOT; k0 += 64) {
        const int kc0 = k0 >> 5;
        const _Float16* bh_base = Bh_g + (size_t)kc0 * NT * 512;
        const _Float16* bl_base = Bl_g + (size_t)kc0 * NT * 512;
#pragma unroll
        for (int i = 0; i < FPW; ++i) {
            int f = wave * FPW + i;
            async_copy16(&Bsh[f * 512 + lane * 8], bh_base + f * 512 + lane * 8);
            async_copy16(&Bsl[f * 512 + lane * 8], bl_base + f * 512 + lane * 8);
        }
#pragma unroll
        for (int i = 0; i < 4; ++i) {
            int flat = tid + i * 256;
            int row = flat >> 3;
            int kk = (flat & 7) << 3;
            int gr = m0 + row;
            if (AFP16) {
                uint4 hv = make_uint4(0u, 0u, 0u, 0u);
                if (gr < M)
                    hv = *(const uint4*)&((const _Float16*)Araw)[(size_t)gr * KTOT + k0 + kk];
                *(uint4*)&Ah[row][kk] = hv;
            } else {
                const float* Af = (const float*)Araw;
                float4 v0 = make_float4(0.f, 0.f, 0.f, 0.f);
                float4 v1 = make_float4(0.f, 0.f, 0.f, 0.f);
                if (gr < M) {
                    v0 = *(const float4*)&Af[(size_t)gr * KTOT + k0 + kk];
                    v1 = *(const float4*)&Af[(size_t)gr * KTOT + k0 + kk + 4];
                }
                f16x8 h;
                h[0] = (_Float16)v0.x; h[1] = (_Float16)v0.y;
                h[2] = (_Float16)v0.z; h[3] = (_Float16)v0.w;
                h[4] = (_Float16)v1.x; h[5] = (_Float16)v1.y;
                h[6] = (_Float16)v1.z; h[7] = (_Float16)v1.w;
                *(f16x8*)&Ah[row][kk] = h;
            }
        }
        __syncthreads();

#pragma unroll
        for (int dkc = 0; dkc < 2; ++dkc) {
            f16x8 a[2];
#pragma unroll
            for (int mt = 0; mt < 2; ++mt)
                a[mt] = *(const f16x8*)&Ah[wave * 32 + mt * 16 + lm][dkc * 32 + q * 8];
#pragma unroll
            for (int nt = 0; nt < NT; ++nt) {
                f16x8 bh = *(const f16x8*)&Bsh[(dkc * NT + nt) * 512 + lane * 8];
                f16x8 bl = *(const f16x8*)&Bsl[(dkc * NT + nt) * 512 + lane * 8];
#pragma unroll
                for (int mt = 0; mt < 2; ++mt) {
                    acc[mt][nt] = __builtin_amdgcn_mfma_f32_16x16x32_f16(a[mt], bh, acc[mt][nt], 0, 0, 0);
                    acc[mt][nt] = __builtin_amdgcn_mfma_f32_16x16x32_f16(a[mt], bl, acc[mt][nt], 0, 0, 0);
                }
            }
        }
        __syncthreads();
    }

#pragma unroll
    for (int mt = 0; mt < 2; ++mt) {
#pragma unroll
        for (int i = 0; i < 4; ++i) {
            int r = m0 + wave * 32 + mt * 16 + q * 4 + i;
            if (r < M) {
                float dv = dinv[r];
#pragma unroll
                for (int nt = 0; nt < NT; ++nt) {
                    C[(size_t)r * BN + nt * 16 + lm] = (_Float16)(acc[mt][nt][i] * dv);
                }
            }
        }
    }
}

// ---------------- aggregation v4: single masked 32-edge gather burst ----------
// Round-0 agg counters: 43% HBM, VALUBusy 41%, occupancy 70% — NO pipe
// saturated => latency-bound. Degree ~ Poisson(16), so the old 16-edge main
// loop ran <=1x/node and most edges went through the 4-edge loop: ONE
// dependent colarr->gather->acc chain in flight per wave. v4 issues one
// straight-line masked burst of 8 chunk-slots (32 edges) per node — covers
// P(d<=32) ~ 99.98% of nodes with 8 gathers + 8 colarr loads in flight.
// Masked slots gather the node's own row (L1-hot, not accumulated). Rare
// d>32 tail: old 4-edge loop. VGPR 24 -> ~60: still 8 waves/SIMD.
__device__ __forceinline__ void acc8(float* a, uint4 v) {
    float2 f0 = __half22float2(*(const __half2*)&v.x);
    float2 f1 = __half22float2(*(const __half2*)&v.y);
    float2 f2 = __half22float2(*(const __half2*)&v.z);
    float2 f3 = __half22float2(*(const __half2*)&v.w);
    a[0] += f0.x; a[1] += f0.y; a[2] += f1.x; a[3] += f1.y;
    a[4] += f2.x; a[5] += f2.y; a[6] += f3.x; a[7] += f3.y;
}

// 128 ch: wave per node; 4 groups of 16 lanes; 8 fp16 channels per lane.
__global__ __launch_bounds__(256) void agg128(const _Float16* __restrict__ g,
                                              const int* __restrict__ rowptr,
                                              const int* __restrict__ colarr,
                                              const float* __restrict__ dinv,
                                              const float* __restrict__ bias,
                                              _Float16* __restrict__ out, int n) {
    int node = blockIdx.x * 4 + (threadIdx.x >> 6);
    int lane = threadIdx.x & 63;
    if (node >= n) return;
    int sel = lane >> 4;        // 0..3
    int co = (lane & 15) << 3;  // 8 fp16 channels

    int beg = rowptr[node];
    int end = rowptr[node + 1];

    float a[8] = {0.f, 0.f, 0.f, 0.f, 0.f, 0.f, 0.f, 0.f};
    if (sel == 0) acc8(a, *(const uint4*)&g[(node << 7) + co]);  // self loop

    // masked straight-line burst: 8 slots x 4 edges = 32 edges fully in flight
    uint4 v[8];
#pragma unroll
    for (int i = 0; i < 8; ++i) {
        int idx = beg + i * 4 + sel;
        int r = (idx < end) ? colarr[idx] : node;   // dummy = own row (L1-hot)
        v[i] = *(const uint4*)&g[(r << 7) + co];
    }
#pragma unroll
    for (int i = 0; i < 8; ++i)
        if (beg + i * 4 + sel < end) acc8(a, v[i]);

    // rare tail (d > 32): 4-edge chunks, group sel covers idx == sel (mod 4)
    for (int p = beg + 32; p + sel < end; p += 4) {
        int r = colarr[p + sel];
        acc8(a, *(const uint4*)&g[(r << 7) + co]);
    }

#pragma unroll
    for (int i = 0; i < 8; ++i) {
        a[i] += __shfl(a[i], lane ^ 16);
        a[i] += __shfl(a[i], lane ^ 32);
    }

    if (sel == 0) {
        float dv = dinv[node];
        float4 b0 = *(const float4*)&bias[co];
        float4 b1 = *(const float4*)&bias[co + 4];
        float o0 = fmaxf(fmaf(a[0], dv, b0.x), 0.f);
        float o1 = fmaxf(fmaf(a[1], dv, b0.y), 0.f);
        float o2 = fmaxf(fmaf(a[2], dv, b0.z), 0.f);
        float o3 = fmaxf(fmaf(a[3], dv, b0.w), 0.f);
        float o4 = fmaxf(fmaf(a[4], dv, b1.x), 0.f);
        float o5 = fmaxf(fmaf(a[5], dv, b1.y), 0.f);
        float o6 = fmaxf(fmaf(a[6], dv, b1.z), 0.f);
        float o7 = fmaxf(fmaf(a[7], dv, b1.w), 0.f);
        __half2 h0 = __floats2half2_rn(o0, o1);
        __half2 h1 = __floats2half2_rn(o2, o3);
        __half2 h2 = __floats2half2_rn(o4, o5);
        __half2 h3 = __floats2half2_rn(o6, o7);
        uint4 pk = make_uint4(*(unsigned*)&h0, *(unsigned*)&h1,
                              *(unsigned*)&h2, *(unsigned*)&h3);
        *(uint4*)&out[(node << 7) + co] = pk;
    }
}

// 64 ch: wave per node; 8 groups of 8 lanes; 8 fp16 channels per lane.
__global__ __launch_bounds__(256) void agg64(const _Float16* __restrict__ g,
                                             const int* __restrict__ rowptr,
                                             const int* __restrict__ colarr,
                                             const float* __restrict__ dinv,
                                             const float* __restrict__ bias,
                                             float* __restrict__ out, int n) {
    int node = blockIdx.x * 4 + (threadIdx.x >> 6);
    int lane = threadIdx.x & 63;
    if (node >= n) return;
    int sel = lane >> 3;       // 0..7
    int co = (lane & 7) << 3;  // 8 fp16 channels

    int beg = rowptr[node];
    int end = rowptr[node + 1];

    float a[8] = {0.f, 0.f, 0.f, 0.f, 0.f, 0.f, 0.f, 0.f};
    if (sel == 0) acc8(a, *(const uint4*)&g[(node << 6) + co]);  // self loop

    // masked burst: 4 slots x 8 edges = 32 edges in flight
    uint4 v[4];
#pragma unroll
    for (int i = 0; i < 4; ++i) {
        int idx = beg + i * 8 + sel;
        int r = (idx < end) ? colarr[idx] : node;
        v[i] = *(const uint4*)&g[(r << 6) + co];
    }
#pragma unroll
    for (int i = 0; i < 4; ++i)
        if (beg + i * 8 + sel < end) acc8(a, v[i]);

    // rare tail (d > 32): 8-edge chunks
    for (int p = beg + 32; p + sel < end; p += 8) {
        int r = colarr[p + sel];
        acc8(a, *(const uint4*)&g[(r << 6) + co]);
    }

#pragma unroll
    for (int i = 0; i < 8; ++i) {
        a[i] += __shfl(a[i], lane ^ 8);
        a[i] += __shfl(a[i], lane ^ 16);
        a[i] += __shfl(a[i], lane ^ 32);
    }

    if (sel == 0) {
        float dv = dinv[node];
        float4 b0 = *(const float4*)&bias[co];
        float4 b1 = *(const float4*)&bias[co + 4];
        float4 oA, oB;
        oA.x = fmaxf(fmaf(a[0], dv, b0.x), 0.f);
        oA.y = fmaxf(fmaf(a[1], dv, b0.y), 0.f);
        oA.z = fmaxf(fmaf(a[2], dv, b0.z), 0.f);
        oA.w = fmaxf(fmaf(a[3], dv, b0.w), 0.f);
        oB.x = fmaxf(fmaf(a[4], dv, b1.x), 0.f);
        oB.y = fmaxf(fmaf(a[5], dv, b1.y), 0.f);
        oB.z = fmaxf(fmaf(a[6], dv, b1.z), 0.f);
        oB.w = fmaxf(fmaf(a[7], dv, b1.w), 0.f);
        *(float4*)&out[(node << 6) + co] = oA;
        *(float4*)&out[(node << 6) + co + 4] = oB;
    }
}

extern "C" void kernel_launch(void* const* d_in, const int* in_sizes, int n_in,
                              void* d_out, int out_size, void* d_ws, size_t ws_size,
                              hipStream_t stream) {
    const float* x  = (const float*)d_in[0];
    const int*   ei = (const int*)d_in[1];
    const float* W1 = (const float*)d_in[2];
    const float* b1 = (const float*)d_in[3];
    const float* W2 = (const float*)d_in[4];
    const float* b2 = (const float*)d_in[5];
    float* out = (float*)d_out;

    const int E = in_sizes[1] / 2;
    const int H1 = in_sizes[3];                 // 128
    const int K1 = in_sizes[2] / H1;            // 256
    const int N = in_sizes[0] / K1;             // 100000
    const int H2 = in_sizes[4] / H1;            // 64
    const int* src = ei;
    const int* dst = ei + E;
    const int NB = (N + 255) >> 8;

    char* ws = (char*)d_ws;
    _Float16* w1th   = (_Float16*)(ws + OFF_W1TH);
    _Float16* w1tl   = (_Float16*)(ws + OFF_W1TL);
    _Float16* w2th   = (_Float16*)(ws + OFF_W2TH);
    _Float16* w2tl   = (_Float16*)(ws + OFF_W2TL);
    int*      bcnt   = (int*)(ws + OFF_BCNT);
    int*      bbase  = (int*)(ws + OFF_BBASE);
    int*      bcur   = (int*)(ws + OFF_BCUR);
    int*      rowptr = (int*)(ws + OFF_ROWPTR);
    float*    dinv   = (float*)(ws + OFF_DINV);
    int*      colarr = (int*)(ws + OFF_COL);
    int*      ebuf   = (int*)(ws + OFF_EBUF);
    _Float16* h1g    = (_Float16*)(ws + OFF_H1G);
    _Float16* h1out  = (_Float16*)(ws + OFF_H1OUT);
    _Float16* h2g    = (_Float16*)(ws + OFF_H1G);   // reuse

    hipMemsetAsync(bcnt, 0, 512 * sizeof(int), stream);
    bincount<<<256, 256, 0, stream>>>(dst, bcnt, E);
    bscan<<<1, 512, 0, stream>>>(bcnt, bbase, bcur, rowptr, NB, N, E);
    binscatter<<<(E + CHUNK - 1) / CHUNK, 256, 0, stream>>>(src, dst, bcur, ebuf, E);
    buildcsr<<<NB, 256, 0, stream>>>(ebuf, bbase, bcnt, rowptr, colarr, dinv, N);

    split_wt_frag<<<(K1 * H1 + 255) / 256, 256, 0, stream>>>(W1, w1th, w1tl, K1, H1);
    split_wt_frag<<<(H1 * H2 + 255) / 256, 256, 0, stream>>>(W2, w2th, w2tl, H1, H2);

    // layer 1
    gemm_f16<128, 256, false><<<(N + 127) / 128, 256, 0, stream>>>(x, w1th, w1tl, dinv, h1g, N);
    agg128<<<(N + 3) / 4, 256, 0, stream>>>(h1g, rowptr, colarr, dinv, b1, h1out, N);

    // layer 2
    gemm_f16<64, 128, true><<<(N + 127) / 128, 256, 0, stream>>>(h1out, w2th, w2tl, dinv, h2g, N);
    agg64<<<(N + 3) / 4, 256, 0, stream>>>(h2g, rowptr, colarr, dinv, b2, out, N);
}